// Round 2
// baseline (237.827 us; speedup 1.0000x reference)
//
#include <hip/hip_runtime.h>
#include <hip/hip_bf16.h>

// Problem constants (from reference)
#define N_NODE 8192
#define H1 512
#define R_EMB 128
#define N_EDGE 262144
#define N_REG 2048

// ---------------- workspace layout (bytes) ----------------
// deg        : [0,            32 KiB)            int32 x 8192
// row_start  : [64 KiB,       64 KiB + 32772)    int32 x 8193
// cursor     : [128 KiB,      160 KiB)           int32 x 8192
// dis        : [160 KiB,      192 KiB)           f32   x 8192
// sorted_src : [256 KiB,      256 KiB + 1 MiB)   int32 x 262144
// h1         : [2 MiB,        18 MiB)            f32   x 8192*512
// g          : [18 MiB,       22 MiB)            f32   x 2048*512
#define OFF_DEG        (0)
#define OFF_ROWSTART   (64 * 1024)
#define OFF_CURSOR     (128 * 1024)
#define OFF_DIS        (160 * 1024)
#define OFF_SORTED     (256 * 1024)
#define OFF_H1         (2 * 1024 * 1024)
#define OFF_G          (18 * 1024 * 1024)

__global__ void hist_kernel(const int* __restrict__ edge, int* __restrict__ deg) {
    int e = blockIdx.x * blockDim.x + threadIdx.x;
    if (e < N_EDGE) {
        int dst = edge[2 * e + 1];
        atomicAdd(&deg[dst], 1);
    }
}

// One block of 1024 threads: exclusive scan of deg[8192] -> row_start, cursor;
// dis = rsqrt(deg + 1) (self loop included in normalization degree).
__global__ void scan_kernel(const int* __restrict__ deg, int* __restrict__ row_start,
                            int* __restrict__ cursor, float* __restrict__ dis) {
    __shared__ int part[1024];
    int t = threadIdx.x;
    int base = t * 8;
    int local[8];
    int sum = 0;
#pragma unroll
    for (int j = 0; j < 8; j++) {
        local[j] = deg[base + j];
        sum += local[j];
    }
    part[t] = sum;
    __syncthreads();
    // Hillis-Steele inclusive scan over 1024 partials
    for (int off = 1; off < 1024; off <<= 1) {
        int v = part[t];
        int add = (t >= off) ? part[t - off] : 0;
        __syncthreads();
        part[t] = v + add;
        __syncthreads();
    }
    int run = part[t] - sum;  // exclusive prefix for this thread's chunk
#pragma unroll
    for (int j = 0; j < 8; j++) {
        row_start[base + j] = run;
        cursor[base + j] = run;
        dis[base + j] = rsqrtf((float)(local[j] + 1));
        run += local[j];
    }
    if (t == 1023) row_start[N_NODE] = run;
}

__global__ void fill_kernel(const int* __restrict__ edge, int* __restrict__ cursor,
                            int* __restrict__ sorted_src) {
    int e = blockIdx.x * blockDim.x + threadIdx.x;
    if (e < N_EDGE) {
        int src = edge[2 * e + 0];
        int dst = edge[2 * e + 1];
        int pos = atomicAdd(&cursor[dst], 1);
        sorted_src[pos] = src;
    }
}

// One block (128 threads) per dst node: h1[d] = relu(dis[d]*(sum_s dis[s]*W1[s] + dis[d]*W1[d]) + b1)
__global__ void layer1_kernel(const float* __restrict__ W1, const float* __restrict__ b1,
                              const int* __restrict__ row_start, const int* __restrict__ sorted_src,
                              const float* __restrict__ dis, float* __restrict__ h1) {
    int d = blockIdx.x;
    int f = threadIdx.x * 4;  // 128 threads x float4 = 512 features
    float disd = dis[d];

    const float4* wrow = (const float4*)(W1 + (size_t)d * H1 + f);
    float4 w = *wrow;
    float4 acc;
    acc.x = w.x * disd; acc.y = w.y * disd; acc.z = w.z * disd; acc.w = w.w * disd;

    int beg = row_start[d], end = row_start[d + 1];
    for (int i = beg; i < end; i++) {
        int s = sorted_src[i];
        float ds = dis[s];
        float4 ws = *(const float4*)(W1 + (size_t)s * H1 + f);
        acc.x += ws.x * ds; acc.y += ws.y * ds; acc.z += ws.z * ds; acc.w += ws.w * ds;
    }
    float4 bb = *(const float4*)(b1 + f);
    float4 o;
    o.x = fmaxf(acc.x * disd + bb.x, 0.0f);
    o.y = fmaxf(acc.y * disd + bb.y, 0.0f);
    o.z = fmaxf(acc.z * disd + bb.z, 0.0f);
    o.w = fmaxf(acc.w * disd + bb.w, 0.0f);
    *(float4*)(h1 + (size_t)d * H1 + f) = o;
}

// One block (128 threads) per target t: g[t] = dis[d]*(sum_s dis[s]*h1[s] + dis[d]*h1[d]), d = reg_id[t]
__global__ void layer2_agg_kernel(const float* __restrict__ h1, const int* __restrict__ reg_id,
                                  const int* __restrict__ row_start, const int* __restrict__ sorted_src,
                                  const float* __restrict__ dis, float* __restrict__ g) {
    int t = blockIdx.x;
    int d = reg_id[t];
    int f = threadIdx.x * 4;
    float disd = dis[d];

    float4 w = *(const float4*)(h1 + (size_t)d * H1 + f);
    float4 acc;
    acc.x = w.x * disd; acc.y = w.y * disd; acc.z = w.z * disd; acc.w = w.w * disd;

    int beg = row_start[d], end = row_start[d + 1];
    for (int i = beg; i < end; i++) {
        int s = sorted_src[i];
        float ds = dis[s];
        float4 ws = *(const float4*)(h1 + (size_t)s * H1 + f);
        acc.x += ws.x * ds; acc.y += ws.y * ds; acc.z += ws.z * ds; acc.w += ws.w * ds;
    }
    float4 o;
    o.x = acc.x * disd; o.y = acc.y * disd; o.z = acc.z * disd; o.w = acc.w * disd;
    *(float4*)(g + (size_t)t * H1 + f) = o;
}

// out[t] = g[t] @ W2 + b2.  M=2048, K=512, N=128.
// Block: 16 rows x 128 cols, 256 threads, each thread 8 outputs (one col, 8 rows).
__global__ void gemm_out_kernel(const float* __restrict__ g, const float* __restrict__ W2,
                                const float* __restrict__ b2, float* __restrict__ out) {
    __shared__ float As[16][32];
    __shared__ float Bs[32][128];
    int block_row = blockIdx.x * 16;
    int c = threadIdx.x & 127;
    int rg = threadIdx.x >> 7;  // 0..1
    float acc[8] = {0, 0, 0, 0, 0, 0, 0, 0};

    for (int kk = 0; kk < H1; kk += 32) {
        for (int i = threadIdx.x; i < 16 * 32; i += 256) {
            int r = i >> 5, k = i & 31;
            As[r][k] = g[(size_t)(block_row + r) * H1 + kk + k];
        }
        for (int i = threadIdx.x; i < 32 * 128; i += 256) {
            int k = i >> 7, cc = i & 127;
            Bs[k][cc] = W2[(size_t)(kk + k) * R_EMB + cc];
        }
        __syncthreads();
#pragma unroll 8
        for (int k = 0; k < 32; k++) {
            float bv = Bs[k][c];
#pragma unroll
            for (int r = 0; r < 8; r++) acc[r] += As[rg * 8 + r][k] * bv;
        }
        __syncthreads();
    }
    float bias = b2[c];
#pragma unroll
    for (int r = 0; r < 8; r++)
        out[(size_t)(block_row + rg * 8 + r) * R_EMB + c] = acc[r] + bias;
}

extern "C" void kernel_launch(void* const* d_in, const int* in_sizes, int n_in,
                              void* d_out, int out_size, void* d_ws, size_t ws_size,
                              hipStream_t stream) {
    const int* reg_id = (const int*)d_in[0];
    const int* edge = (const int*)d_in[1];
    const float* W1 = (const float*)d_in[2];
    const float* b1 = (const float*)d_in[3];
    const float* W2 = (const float*)d_in[4];
    const float* b2 = (const float*)d_in[5];
    float* out = (float*)d_out;

    char* ws = (char*)d_ws;
    int* deg = (int*)(ws + OFF_DEG);
    int* row_start = (int*)(ws + OFF_ROWSTART);
    int* cursor = (int*)(ws + OFF_CURSOR);
    float* dis = (float*)(ws + OFF_DIS);
    int* sorted_src = (int*)(ws + OFF_SORTED);
    float* h1 = (float*)(ws + OFF_H1);
    float* g = (float*)(ws + OFF_G);

    // deg must start at zero every call (ws is poisoned with 0xAA each replay)
    hipMemsetAsync(deg, 0, N_NODE * sizeof(int), stream);

    hist_kernel<<<N_EDGE / 256, 256, 0, stream>>>(edge, deg);
    scan_kernel<<<1, 1024, 0, stream>>>(deg, row_start, cursor, dis);
    fill_kernel<<<N_EDGE / 256, 256, 0, stream>>>(edge, cursor, sorted_src);
    layer1_kernel<<<N_NODE, 128, 0, stream>>>(W1, b1, row_start, sorted_src, dis, h1);
    layer2_agg_kernel<<<N_REG, 128, 0, stream>>>(h1, reg_id, row_start, sorted_src, dis, g);
    gemm_out_kernel<<<N_REG / 16, 256, 0, stream>>>(g, W2, b2, out);
}

// Round 3
// 206.244 us; speedup vs baseline: 1.1531x; 1.1531x over previous
//
#include <hip/hip_runtime.h>
#include <hip/hip_bf16.h>

typedef unsigned int u32;

// Problem constants (from reference)
#define N_NODE 8192
#define H1 512
#define R_EMB 128
#define N_EDGE 262144
#define N_REG 2048

// ---------------- workspace layout (bytes) ----------------
#define OFF_DEG        (0)               // int32 x 8192
#define OFF_ROWSTART   (64 * 1024)       // int32 x 8193
#define OFF_CURSOR     (128 * 1024)      // int32 x 8192
#define OFF_DIS        (160 * 1024)      // f32   x 8192
#define OFF_SORTED     (256 * 1024)      // int32 x 262144 (1 MiB)
#define OFF_W1S        (2 * 1024 * 1024)   // bf16 pairs: u32[8192][256]  (8 MiB)  W1s = dis[s]*W1[s]
#define OFF_H1S        (10 * 1024 * 1024)  // bf16 pairs: u32[8192][256]  (8 MiB)  h1s = dis[d]*relu(...)
#define OFF_G          (18 * 1024 * 1024)  // f32 [2048][512] (4 MiB)

__device__ inline u32 rne_bf16(float f) {
    u32 u = __float_as_uint(f);
    u += 0x7fffu + ((u >> 16) & 1u);
    return u >> 16;
}
__device__ inline float bf_lo(u32 u) { return __uint_as_float(u << 16); }
__device__ inline float bf_hi(u32 u) { return __uint_as_float(u & 0xffff0000u); }

__global__ void hist_kernel(const int* __restrict__ edge, int* __restrict__ deg) {
    int e = blockIdx.x * blockDim.x + threadIdx.x;
    if (e < N_EDGE) {
        int dst = edge[2 * e + 1];
        atomicAdd(&deg[dst], 1);
    }
}

// One block of 1024 threads: exclusive scan of deg[8192] -> row_start, cursor;
// dis = rsqrt(deg + 1) (self loop included in normalization degree).
__global__ void scan_kernel(const int* __restrict__ deg, int* __restrict__ row_start,
                            int* __restrict__ cursor, float* __restrict__ dis) {
    __shared__ int part[1024];
    int t = threadIdx.x;
    int base = t * 8;
    int local[8];
    int sum = 0;
#pragma unroll
    for (int j = 0; j < 8; j++) {
        local[j] = deg[base + j];
        sum += local[j];
    }
    part[t] = sum;
    __syncthreads();
    for (int off = 1; off < 1024; off <<= 1) {
        int v = part[t];
        int add = (t >= off) ? part[t - off] : 0;
        __syncthreads();
        part[t] = v + add;
        __syncthreads();
    }
    int run = part[t] - sum;  // exclusive prefix
#pragma unroll
    for (int j = 0; j < 8; j++) {
        row_start[base + j] = run;
        cursor[base + j] = run;
        dis[base + j] = rsqrtf((float)(local[j] + 1));
        run += local[j];
    }
    if (t == 1023) row_start[N_NODE] = run;
}

__global__ void fill_kernel(const int* __restrict__ edge, int* __restrict__ cursor,
                            int* __restrict__ sorted_src) {
    int e = blockIdx.x * blockDim.x + threadIdx.x;
    if (e < N_EDGE) {
        int src = edge[2 * e + 0];
        int dst = edge[2 * e + 1];
        int pos = atomicAdd(&cursor[dst], 1);
        sorted_src[pos] = src;
    }
}

// W1s[row] = bf16(dis[row] * W1[row]); one thread per bf16-pair (2M threads).
__global__ void convert_kernel(const float* __restrict__ W1, const float* __restrict__ dis,
                               u32* __restrict__ W1s) {
    int idx = blockIdx.x * blockDim.x + threadIdx.x;   // 0 .. 8192*256-1
    int row = idx >> 8;
    int pc = idx & 255;
    float d = dis[row];
    float2 f = *(const float2*)(W1 + ((size_t)row << 9) + (pc << 1));
    W1s[idx] = rne_bf16(f.x * d) | (rne_bf16(f.y * d) << 16);
}

// One block (64 threads) per dst node. acc = W1s[d] + sum_s W1s[s]  (all pre-scaled by dis[src]).
// h1s[d] = dis[d] * relu(dis[d]*acc + b1), stored bf16.
__global__ void layer1_kernel(const u32* __restrict__ W1s, const float* __restrict__ b1,
                              const int* __restrict__ row_start, const int* __restrict__ sorted_src,
                              const float* __restrict__ dis, u32* __restrict__ h1s) {
    int d = blockIdx.x;
    int t = threadIdx.x;  // 0..63, each owns 8 features
    float disd = dis[d];
    const uint4* base = (const uint4*)W1s;  // 64 uint4 per row

    uint4 w = base[(d << 6) + t];
    float a0 = bf_lo(w.x), a1 = bf_hi(w.x), a2 = bf_lo(w.y), a3 = bf_hi(w.y);
    float a4 = bf_lo(w.z), a5 = bf_hi(w.z), a6 = bf_lo(w.w), a7 = bf_hi(w.w);

    int beg = row_start[d], end = row_start[d + 1];
    for (int i = beg; i < end; i++) {
        int s = sorted_src[i];
        uint4 ws = base[(s << 6) + t];
        a0 += bf_lo(ws.x); a1 += bf_hi(ws.x);
        a2 += bf_lo(ws.y); a3 += bf_hi(ws.y);
        a4 += bf_lo(ws.z); a5 += bf_hi(ws.z);
        a6 += bf_lo(ws.w); a7 += bf_hi(ws.w);
    }
    int f = t * 8;
    float4 bl = *(const float4*)(b1 + f);
    float4 bh = *(const float4*)(b1 + f + 4);
    float o0 = fmaxf(a0 * disd + bl.x, 0.0f) * disd;
    float o1 = fmaxf(a1 * disd + bl.y, 0.0f) * disd;
    float o2 = fmaxf(a2 * disd + bl.z, 0.0f) * disd;
    float o3 = fmaxf(a3 * disd + bl.w, 0.0f) * disd;
    float o4 = fmaxf(a4 * disd + bh.x, 0.0f) * disd;
    float o5 = fmaxf(a5 * disd + bh.y, 0.0f) * disd;
    float o6 = fmaxf(a6 * disd + bh.z, 0.0f) * disd;
    float o7 = fmaxf(a7 * disd + bh.w, 0.0f) * disd;
    uint4 o;
    o.x = rne_bf16(o0) | (rne_bf16(o1) << 16);
    o.y = rne_bf16(o2) | (rne_bf16(o3) << 16);
    o.z = rne_bf16(o4) | (rne_bf16(o5) << 16);
    o.w = rne_bf16(o6) | (rne_bf16(o7) << 16);
    ((uint4*)h1s)[(d << 6) + t] = o;
}

// One block (64 threads) per target: g[t] = dis[d]*(sum_s h1s[s] + h1s[d]), d = reg_id[t]
__global__ void layer2_agg_kernel(const u32* __restrict__ h1s, const int* __restrict__ reg_id,
                                  const int* __restrict__ row_start, const int* __restrict__ sorted_src,
                                  const float* __restrict__ dis, float* __restrict__ g) {
    int tgt = blockIdx.x;
    int d = reg_id[tgt];
    int t = threadIdx.x;
    float disd = dis[d];
    const uint4* base = (const uint4*)h1s;

    uint4 w = base[(d << 6) + t];
    float a0 = bf_lo(w.x), a1 = bf_hi(w.x), a2 = bf_lo(w.y), a3 = bf_hi(w.y);
    float a4 = bf_lo(w.z), a5 = bf_hi(w.z), a6 = bf_lo(w.w), a7 = bf_hi(w.w);

    int beg = row_start[d], end = row_start[d + 1];
    for (int i = beg; i < end; i++) {
        int s = sorted_src[i];
        uint4 ws = base[(s << 6) + t];
        a0 += bf_lo(ws.x); a1 += bf_hi(ws.x);
        a2 += bf_lo(ws.y); a3 += bf_hi(ws.y);
        a4 += bf_lo(ws.z); a5 += bf_hi(ws.z);
        a6 += bf_lo(ws.w); a7 += bf_hi(ws.w);
    }
    int f = t * 8;
    float4 lo, hi;
    lo.x = a0 * disd; lo.y = a1 * disd; lo.z = a2 * disd; lo.w = a3 * disd;
    hi.x = a4 * disd; hi.y = a5 * disd; hi.z = a6 * disd; hi.w = a7 * disd;
    *(float4*)(g + (size_t)tgt * H1 + f) = lo;
    *(float4*)(g + (size_t)tgt * H1 + f + 4) = hi;
}

// out[t] = g[t] @ W2 + b2.  M=2048, K=512, N=128.
__global__ void gemm_out_kernel(const float* __restrict__ g, const float* __restrict__ W2,
                                const float* __restrict__ b2, float* __restrict__ out) {
    __shared__ float As[16][32];
    __shared__ float Bs[32][128];
    int block_row = blockIdx.x * 16;
    int c = threadIdx.x & 127;
    int rg = threadIdx.x >> 7;  // 0..1
    float acc[8] = {0, 0, 0, 0, 0, 0, 0, 0};

    for (int kk = 0; kk < H1; kk += 32) {
        for (int i = threadIdx.x; i < 16 * 32; i += 256) {
            int r = i >> 5, k = i & 31;
            As[r][k] = g[(size_t)(block_row + r) * H1 + kk + k];
        }
        for (int i = threadIdx.x; i < 32 * 128; i += 256) {
            int k = i >> 7, cc = i & 127;
            Bs[k][cc] = W2[(size_t)(kk + k) * R_EMB + cc];
        }
        __syncthreads();
#pragma unroll 8
        for (int k = 0; k < 32; k++) {
            float bv = Bs[k][c];
#pragma unroll
            for (int r = 0; r < 8; r++) acc[r] += As[rg * 8 + r][k] * bv;
        }
        __syncthreads();
    }
    float bias = b2[c];
#pragma unroll
    for (int r = 0; r < 8; r++)
        out[(size_t)(block_row + rg * 8 + r) * R_EMB + c] = acc[r] + bias;
}

extern "C" void kernel_launch(void* const* d_in, const int* in_sizes, int n_in,
                              void* d_out, int out_size, void* d_ws, size_t ws_size,
                              hipStream_t stream) {
    const int* reg_id = (const int*)d_in[0];
    const int* edge = (const int*)d_in[1];
    const float* W1 = (const float*)d_in[2];
    const float* b1 = (const float*)d_in[3];
    const float* W2 = (const float*)d_in[4];
    const float* b2 = (const float*)d_in[5];
    float* out = (float*)d_out;

    char* ws = (char*)d_ws;
    int* deg = (int*)(ws + OFF_DEG);
    int* row_start = (int*)(ws + OFF_ROWSTART);
    int* cursor = (int*)(ws + OFF_CURSOR);
    float* dis = (float*)(ws + OFF_DIS);
    int* sorted_src = (int*)(ws + OFF_SORTED);
    u32* W1s = (u32*)(ws + OFF_W1S);
    u32* h1s = (u32*)(ws + OFF_H1S);
    float* g = (float*)(ws + OFF_G);

    hipMemsetAsync(deg, 0, N_NODE * sizeof(int), stream);

    hist_kernel<<<N_EDGE / 256, 256, 0, stream>>>(edge, deg);
    scan_kernel<<<1, 1024, 0, stream>>>(deg, row_start, cursor, dis);
    convert_kernel<<<(N_NODE * 256) / 256, 256, 0, stream>>>(W1, dis, W1s);
    fill_kernel<<<N_EDGE / 256, 256, 0, stream>>>(edge, cursor, sorted_src);
    layer1_kernel<<<N_NODE, 64, 0, stream>>>(W1s, b1, row_start, sorted_src, dis, h1s);
    layer2_agg_kernel<<<N_REG, 64, 0, stream>>>(h1s, reg_id, row_start, sorted_src, dis, g);
    gemm_out_kernel<<<N_REG / 16, 256, 0, stream>>>(g, W2, b2, out);
}

// Round 4
// 163.435 us; speedup vs baseline: 1.4552x; 1.2619x over previous
//
#include <hip/hip_runtime.h>
#include <hip/hip_bf16.h>

typedef unsigned int u32;

// Problem constants (from reference)
#define N_NODE 8192
#define H1 512
#define R_EMB 128
#define N_EDGE 262144
#define N_REG 2048

// ---------------- workspace layout (bytes) ----------------
#define OFF_DEG        (0)               // int32 x 8192
#define OFF_ROWSTART   (64 * 1024)       // int32 x 8193
#define OFF_CURSOR     (128 * 1024)      // int32 x 8192
#define OFF_DIS        (160 * 1024)      // f32   x 8192
#define OFF_SORTED     (256 * 1024)      // int32 x 262144 (1 MiB)
#define OFF_W1S        (2 * 1024 * 1024)   // bf16 pairs: u32[8192][256] (8 MiB)  W1s = dis[s]*W1[s]
#define OFF_H1S        (10 * 1024 * 1024)  // bf16 pairs: u32[8192][256] (8 MiB)  h1s = dis[d]*relu(...)
#define OFF_W2T        (18 * 1024 * 1024)  // bf16 pairs: u32[128][256]  (128 KiB) W2 transposed
#define OFF_G          (19 * 1024 * 1024)  // bf16 pairs: u32[2048][256] (2 MiB)

__device__ inline u32 rne_bf16(float f) {
    u32 u = __float_as_uint(f);
    u += 0x7fffu + ((u >> 16) & 1u);
    return u >> 16;
}
__device__ inline float bf_lo(u32 u) { return __uint_as_float(u << 16); }
__device__ inline float bf_hi(u32 u) { return __uint_as_float(u & 0xffff0000u); }

using frag_ab = __attribute__((ext_vector_type(8))) short;  // 8 bf16 (4 VGPRs)
using frag_cd = __attribute__((ext_vector_type(4))) float;  // 4 fp32

__global__ void hist_kernel(const int* __restrict__ edge, int* __restrict__ deg) {
    int e = blockIdx.x * blockDim.x + threadIdx.x;
    if (e < N_EDGE) {
        int dst = edge[2 * e + 1];
        atomicAdd(&deg[dst], 1);
    }
}

// One block of 1024 threads: exclusive scan of deg[8192] -> row_start, cursor;
// dis = rsqrt(deg + 1) (self loop included in normalization degree).
__global__ void scan_kernel(const int* __restrict__ deg, int* __restrict__ row_start,
                            int* __restrict__ cursor, float* __restrict__ dis) {
    __shared__ int part[1024];
    int t = threadIdx.x;
    int base = t * 8;
    int local[8];
    int sum = 0;
#pragma unroll
    for (int j = 0; j < 8; j++) {
        local[j] = deg[base + j];
        sum += local[j];
    }
    part[t] = sum;
    __syncthreads();
    for (int off = 1; off < 1024; off <<= 1) {
        int v = part[t];
        int add = (t >= off) ? part[t - off] : 0;
        __syncthreads();
        part[t] = v + add;
        __syncthreads();
    }
    int run = part[t] - sum;  // exclusive prefix
#pragma unroll
    for (int j = 0; j < 8; j++) {
        row_start[base + j] = run;
        cursor[base + j] = run;
        dis[base + j] = rsqrtf((float)(local[j] + 1));
        run += local[j];
    }
    if (t == 1023) row_start[N_NODE] = run;
}

__global__ void fill_kernel(const int* __restrict__ edge, int* __restrict__ cursor,
                            int* __restrict__ sorted_src) {
    int e = blockIdx.x * blockDim.x + threadIdx.x;
    if (e < N_EDGE) {
        int src = edge[2 * e + 0];
        int dst = edge[2 * e + 1];
        int pos = atomicAdd(&cursor[dst], 1);
        sorted_src[pos] = src;
    }
}

// W1s[row] = bf16(dis[row] * W1[row]); one thread per bf16-pair (2M threads).
__global__ void convert_kernel(const float* __restrict__ W1, const float* __restrict__ dis,
                               u32* __restrict__ W1s) {
    int idx = blockIdx.x * blockDim.x + threadIdx.x;   // 0 .. 8192*256-1
    int row = idx >> 8;
    int pc = idx & 255;
    float d = dis[row];
    float2 f = *(const float2*)(W1 + ((size_t)row << 9) + (pc << 1));
    W1s[idx] = rne_bf16(f.x * d) | (rne_bf16(f.y * d) << 16);
}

// w2t[j][p] packs bf16(W2[2p][j]), bf16(W2[2p+1][j]).  32768 threads.
__global__ void convert_w2t_kernel(const float* __restrict__ W2, u32* __restrict__ w2t) {
    int idx = blockIdx.x * blockDim.x + threadIdx.x;  // 0..32767
    int j = idx >> 8;     // 0..127 (output column)
    int p = idx & 255;    // k-pair
    float a = W2[(size_t)(2 * p) * R_EMB + j];
    float b = W2[(size_t)(2 * p + 1) * R_EMB + j];
    w2t[idx] = rne_bf16(a) | (rne_bf16(b) << 16);
}

// One block (64 threads) per dst node. acc = W1s[d] + sum_s W1s[s]  (pre-scaled by dis[src]).
// h1s[d] = dis[d] * relu(dis[d]*acc + b1), stored bf16.
__global__ void layer1_kernel(const u32* __restrict__ W1s, const float* __restrict__ b1,
                              const int* __restrict__ row_start, const int* __restrict__ sorted_src,
                              const float* __restrict__ dis, u32* __restrict__ h1s) {
    int d = blockIdx.x;
    int t = threadIdx.x;  // 0..63, each owns 8 features
    float disd = dis[d];
    const uint4* base = (const uint4*)W1s;  // 64 uint4 per row

    uint4 w = base[(d << 6) + t];
    float a0 = bf_lo(w.x), a1 = bf_hi(w.x), a2 = bf_lo(w.y), a3 = bf_hi(w.y);
    float a4 = bf_lo(w.z), a5 = bf_hi(w.z), a6 = bf_lo(w.w), a7 = bf_hi(w.w);

    int beg = row_start[d], end = row_start[d + 1];
    for (int i = beg; i < end; i++) {
        int s = sorted_src[i];
        uint4 ws = base[(s << 6) + t];
        a0 += bf_lo(ws.x); a1 += bf_hi(ws.x);
        a2 += bf_lo(ws.y); a3 += bf_hi(ws.y);
        a4 += bf_lo(ws.z); a5 += bf_hi(ws.z);
        a6 += bf_lo(ws.w); a7 += bf_hi(ws.w);
    }
    int f = t * 8;
    float4 bl = *(const float4*)(b1 + f);
    float4 bh = *(const float4*)(b1 + f + 4);
    float o0 = fmaxf(a0 * disd + bl.x, 0.0f) * disd;
    float o1 = fmaxf(a1 * disd + bl.y, 0.0f) * disd;
    float o2 = fmaxf(a2 * disd + bl.z, 0.0f) * disd;
    float o3 = fmaxf(a3 * disd + bl.w, 0.0f) * disd;
    float o4 = fmaxf(a4 * disd + bh.x, 0.0f) * disd;
    float o5 = fmaxf(a5 * disd + bh.y, 0.0f) * disd;
    float o6 = fmaxf(a6 * disd + bh.z, 0.0f) * disd;
    float o7 = fmaxf(a7 * disd + bh.w, 0.0f) * disd;
    uint4 o;
    o.x = rne_bf16(o0) | (rne_bf16(o1) << 16);
    o.y = rne_bf16(o2) | (rne_bf16(o3) << 16);
    o.z = rne_bf16(o4) | (rne_bf16(o5) << 16);
    o.w = rne_bf16(o6) | (rne_bf16(o7) << 16);
    ((uint4*)h1s)[(d << 6) + t] = o;
}

// One block (64 threads) per target: g[t] = dis[d]*(sum_s h1s[s] + h1s[d]), d = reg_id[t].
// Output packed bf16 for the MFMA GEMM.
__global__ void layer2_agg_kernel(const u32* __restrict__ h1s, const int* __restrict__ reg_id,
                                  const int* __restrict__ row_start, const int* __restrict__ sorted_src,
                                  const float* __restrict__ dis, u32* __restrict__ g_bf) {
    int tgt = blockIdx.x;
    int d = reg_id[tgt];
    int t = threadIdx.x;
    float disd = dis[d];
    const uint4* base = (const uint4*)h1s;

    uint4 w = base[(d << 6) + t];
    float a0 = bf_lo(w.x), a1 = bf_hi(w.x), a2 = bf_lo(w.y), a3 = bf_hi(w.y);
    float a4 = bf_lo(w.z), a5 = bf_hi(w.z), a6 = bf_lo(w.w), a7 = bf_hi(w.w);

    int beg = row_start[d], end = row_start[d + 1];
    for (int i = beg; i < end; i++) {
        int s = sorted_src[i];
        uint4 ws = base[(s << 6) + t];
        a0 += bf_lo(ws.x); a1 += bf_hi(ws.x);
        a2 += bf_lo(ws.y); a3 += bf_hi(ws.y);
        a4 += bf_lo(ws.z); a5 += bf_hi(ws.z);
        a6 += bf_lo(ws.w); a7 += bf_hi(ws.w);
    }
    uint4 o;
    o.x = rne_bf16(a0 * disd) | (rne_bf16(a1 * disd) << 16);
    o.y = rne_bf16(a2 * disd) | (rne_bf16(a3 * disd) << 16);
    o.z = rne_bf16(a4 * disd) | (rne_bf16(a5 * disd) << 16);
    o.w = rne_bf16(a6 * disd) | (rne_bf16(a7 * disd) << 16);
    ((uint4*)g_bf)[(tgt << 6) + t] = o;
}

// out = g @ W2 + b2 via MFMA.  M=2048, K=512, N=128.
// One wave per 16x16 output tile: 1024 waves = 256 blocks x 4 waves.
// A-frag: row = lane&15 of g, k = (lane>>4)*8 + e (contiguous bf16).
// B-frag: col = lane&15 -> row of W2T, same k packing.
// D: col = lane&15, row = (lane>>4)*4 + reg  [m89-verified].
__global__ void gemm_out_mfma(const u32* __restrict__ g_bf, const u32* __restrict__ w2t_bf,
                              const float* __restrict__ b2, float* __restrict__ out) {
    int w = blockIdx.x * 4 + (threadIdx.x >> 6);   // 0..1023
    int lane = threadIdx.x & 63;
    int tm = w >> 3;        // 0..127
    int tn = w & 7;         // 0..7
    int r15 = lane & 15;
    int kb4 = (lane >> 4) << 2;   // u32 offset of this lane's k-block

    const uint4* arow = (const uint4*)(g_bf + ((tm * 16 + r15) << 8) + kb4);
    const uint4* brow = (const uint4*)(w2t_bf + ((tn * 16 + r15) << 8) + kb4);
    frag_cd acc = {0.0f, 0.0f, 0.0f, 0.0f};
#pragma unroll
    for (int kk = 0; kk < 16; kk++) {
        uint4 av = arow[kk * 4];   // +16 u32 per K-step of 32
        uint4 bv = brow[kk * 4];
        acc = __builtin_amdgcn_mfma_f32_16x16x32_bf16(*(frag_ab*)&av, *(frag_ab*)&bv, acc, 0, 0, 0);
    }
    int col = tn * 16 + r15;
    int row0 = tm * 16 + ((lane >> 4) << 2);
    float bias = b2[col];
#pragma unroll
    for (int r = 0; r < 4; r++)
        out[(size_t)(row0 + r) * R_EMB + col] = acc[r] + bias;
}

extern "C" void kernel_launch(void* const* d_in, const int* in_sizes, int n_in,
                              void* d_out, int out_size, void* d_ws, size_t ws_size,
                              hipStream_t stream) {
    const int* reg_id = (const int*)d_in[0];
    const int* edge = (const int*)d_in[1];
    const float* W1 = (const float*)d_in[2];
    const float* b1 = (const float*)d_in[3];
    const float* W2 = (const float*)d_in[4];
    const float* b2 = (const float*)d_in[5];
    float* out = (float*)d_out;

    char* ws = (char*)d_ws;
    int* deg = (int*)(ws + OFF_DEG);
    int* row_start = (int*)(ws + OFF_ROWSTART);
    int* cursor = (int*)(ws + OFF_CURSOR);
    float* dis = (float*)(ws + OFF_DIS);
    int* sorted_src = (int*)(ws + OFF_SORTED);
    u32* W1s = (u32*)(ws + OFF_W1S);
    u32* h1s = (u32*)(ws + OFF_H1S);
    u32* w2t = (u32*)(ws + OFF_W2T);
    u32* g_bf = (u32*)(ws + OFF_G);

    hipMemsetAsync(deg, 0, N_NODE * sizeof(int), stream);

    hist_kernel<<<N_EDGE / 256, 256, 0, stream>>>(edge, deg);
    scan_kernel<<<1, 1024, 0, stream>>>(deg, row_start, cursor, dis);
    convert_kernel<<<(N_NODE * 256) / 256, 256, 0, stream>>>(W1, dis, W1s);
    convert_w2t_kernel<<<(N_REG * 16) / 256, 256, 0, stream>>>(W2, w2t);  // 128 blocks
    fill_kernel<<<N_EDGE / 256, 256, 0, stream>>>(edge, cursor, sorted_src);
    layer1_kernel<<<N_NODE, 64, 0, stream>>>(W1s, b1, row_start, sorted_src, dis, h1s);
    layer2_agg_kernel<<<N_REG, 64, 0, stream>>>(h1s, reg_id, row_start, sorted_src, dis, g_bf);
    gemm_out_mfma<<<256, 256, 0, stream>>>(g_bf, w2t, b2, out);
}

// Round 7
// 149.654 us; speedup vs baseline: 1.5892x; 1.0921x over previous
//
#include <hip/hip_runtime.h>
#include <hip/hip_bf16.h>

typedef unsigned int u32;

// Problem constants (from reference)
#define N_NODE 8192
#define H1 512
#define R_EMB 128
#define N_EDGE 262144
#define N_REG 2048

// ---------------- workspace layout (bytes) ----------------
#define OFF_DEG        (0)               // int32 x 8192
#define OFF_ROWSTART   (64 * 1024)       // int32 x 8193
#define OFF_CURSOR     (128 * 1024)      // int32 x 8192
#define OFF_DIS        (160 * 1024)      // f32   x 8192
#define OFF_SORTED     (256 * 1024)      // int32 x 262144 (1 MiB)
#define OFF_W1S        (2 * 1024 * 1024)   // bf16 pairs: u32[8192][256] (8 MiB)  W1s = dis[s]*W1[s]
#define OFF_H1S        (10 * 1024 * 1024)  // bf16 pairs: u32[8192][256] (8 MiB)  h1s = dis[d]*relu(...)
#define OFF_W2T        (18 * 1024 * 1024)  // bf16 pairs: u32[128][256]  (128 KiB) W2 transposed
#define OFF_G          (19 * 1024 * 1024)  // bf16 pairs: u32[2048][256] (2 MiB)

__device__ inline u32 rne_bf16(float f) {
    u32 u = __float_as_uint(f);
    u += 0x7fffu + ((u >> 16) & 1u);
    return u >> 16;
}
__device__ inline float bf_lo(u32 u) { return __uint_as_float(u << 16); }
__device__ inline float bf_hi(u32 u) { return __uint_as_float(u & 0xffff0000u); }

using frag_ab = __attribute__((ext_vector_type(8))) short;  // 8 bf16 (4 VGPRs)
using frag_cd = __attribute__((ext_vector_type(4))) float;  // 4 fp32

__global__ void hist_kernel(const int* __restrict__ edge, int* __restrict__ deg) {
    int e = blockIdx.x * blockDim.x + threadIdx.x;
    if (e < N_EDGE) {
        int dst = edge[2 * e + 1];
        atomicAdd(&deg[dst], 1);
    }
}

// 1024 threads: exclusive scan of deg[8192] -> row_start, cursor; dis = rsqrt(deg+1).
// Wave-shuffle scan: 2 barriers total (vs 20 in Hillis-Steele version).
__global__ void scan_kernel(const int* __restrict__ deg, int* __restrict__ row_start,
                            int* __restrict__ cursor, float* __restrict__ dis) {
    __shared__ int wtot[16];
    __shared__ int wpre[16];
    int t = threadIdx.x;
    int lane = t & 63;
    int wv = t >> 6;
    int base = t * 8;
    int local[8];
    int sum = 0;
#pragma unroll
    for (int j = 0; j < 8; j++) {
        local[j] = deg[base + j];
        sum += local[j];
    }
    // wave-level inclusive scan of per-thread sums
    int sc = sum;
#pragma unroll
    for (int off = 1; off < 64; off <<= 1) {
        int y = __shfl_up(sc, off, 64);
        if (lane >= off) sc += y;
    }
    if (lane == 63) wtot[wv] = sc;
    __syncthreads();
    if (wv == 0 && lane < 16) {
        int v = wtot[lane];
        int s2 = v;
#pragma unroll
        for (int off = 1; off < 16; off <<= 1) {
            int y = __shfl_up(s2, off, 64);
            if (lane >= off) s2 += y;
        }
        wpre[lane] = s2 - v;  // exclusive wave prefix
    }
    __syncthreads();
    int run = wpre[wv] + (sc - sum);  // exclusive prefix for this thread's chunk
#pragma unroll
    for (int j = 0; j < 8; j++) {
        row_start[base + j] = run;
        cursor[base + j] = run;
        dis[base + j] = rsqrtf((float)(local[j] + 1));
        run += local[j];
    }
    if (t == 1023) row_start[N_NODE] = run;
}

// Fused: [0,1024) fill CSR, [1024,9216) convert W1 -> bf16*dis, [9216,9344) W2^T -> bf16.
__global__ void prep_kernel(const int* __restrict__ edge, int* __restrict__ cursor,
                            int* __restrict__ sorted_src,
                            const float* __restrict__ W1, const float* __restrict__ dis,
                            u32* __restrict__ W1s,
                            const float* __restrict__ W2, u32* __restrict__ w2t) {
    int bid = blockIdx.x;
    if (bid < 1024) {
        int e = bid * 256 + threadIdx.x;
        int src = edge[2 * e + 0];
        int dst = edge[2 * e + 1];
        int pos = atomicAdd(&cursor[dst], 1);
        sorted_src[pos] = src;
    } else if (bid < 1024 + 8192) {
        int idx = (bid - 1024) * 256 + threadIdx.x;  // 0 .. 2M-1
        int row = idx >> 8;
        int pc = idx & 255;
        float d = dis[row];
        float2 f = *(const float2*)(W1 + ((size_t)row << 9) + (pc << 1));
        W1s[idx] = rne_bf16(f.x * d) | (rne_bf16(f.y * d) << 16);
    } else {
        int idx = (bid - 9216) * 256 + threadIdx.x;  // 0..32767
        int j = idx >> 8;     // output column
        int p = idx & 255;    // k-pair
        float a = W2[(size_t)(2 * p) * R_EMB + j];
        float b = W2[(size_t)(2 * p + 1) * R_EMB + j];
        w2t[idx] = rne_bf16(a) | (rne_bf16(b) << 16);
    }
}

// One block (64 threads) per dst node. acc = W1s[d] + sum_s W1s[s]  (pre-scaled by dis[src]).
// h1s[d] = dis[d] * relu(dis[d]*acc + b1), stored bf16. Edge loop unrolled x2, dual accumulators.
__global__ void layer1_kernel(const u32* __restrict__ W1s, const float* __restrict__ b1,
                              const int* __restrict__ row_start, const int* __restrict__ sorted_src,
                              const float* __restrict__ dis, u32* __restrict__ h1s) {
    int d = blockIdx.x;
    int t = threadIdx.x;  // 0..63, each owns 8 features
    float disd = dis[d];
    const uint4* base = (const uint4*)W1s;  // 64 uint4 per row

    uint4 w = base[(d << 6) + t];
    float a0 = bf_lo(w.x), a1 = bf_hi(w.x), a2 = bf_lo(w.y), a3 = bf_hi(w.y);
    float a4 = bf_lo(w.z), a5 = bf_hi(w.z), a6 = bf_lo(w.w), a7 = bf_hi(w.w);
    float c0 = 0, c1 = 0, c2 = 0, c3 = 0, c4 = 0, c5 = 0, c6 = 0, c7 = 0;

    int beg = row_start[d], end = row_start[d + 1];
    int i = beg;
    if ((end - beg) & 1) {
        int s = sorted_src[i++];
        uint4 ws = base[(s << 6) + t];
        a0 += bf_lo(ws.x); a1 += bf_hi(ws.x);
        a2 += bf_lo(ws.y); a3 += bf_hi(ws.y);
        a4 += bf_lo(ws.z); a5 += bf_hi(ws.z);
        a6 += bf_lo(ws.w); a7 += bf_hi(ws.w);
    }
    for (; i < end; i += 2) {
        int s0 = sorted_src[i];
        int s1 = sorted_src[i + 1];
        uint4 w0 = base[(s0 << 6) + t];
        uint4 w1 = base[(s1 << 6) + t];
        a0 += bf_lo(w0.x); a1 += bf_hi(w0.x);
        a2 += bf_lo(w0.y); a3 += bf_hi(w0.y);
        a4 += bf_lo(w0.z); a5 += bf_hi(w0.z);
        a6 += bf_lo(w0.w); a7 += bf_hi(w0.w);
        c0 += bf_lo(w1.x); c1 += bf_hi(w1.x);
        c2 += bf_lo(w1.y); c3 += bf_hi(w1.y);
        c4 += bf_lo(w1.z); c5 += bf_hi(w1.z);
        c6 += bf_lo(w1.w); c7 += bf_hi(w1.w);
    }
    a0 += c0; a1 += c1; a2 += c2; a3 += c3;
    a4 += c4; a5 += c5; a6 += c6; a7 += c7;

    int f = t * 8;
    float4 bl = *(const float4*)(b1 + f);
    float4 bh = *(const float4*)(b1 + f + 4);
    float o0 = fmaxf(a0 * disd + bl.x, 0.0f) * disd;
    float o1 = fmaxf(a1 * disd + bl.y, 0.0f) * disd;
    float o2 = fmaxf(a2 * disd + bl.z, 0.0f) * disd;
    float o3 = fmaxf(a3 * disd + bl.w, 0.0f) * disd;
    float o4 = fmaxf(a4 * disd + bh.x, 0.0f) * disd;
    float o5 = fmaxf(a5 * disd + bh.y, 0.0f) * disd;
    float o6 = fmaxf(a6 * disd + bh.z, 0.0f) * disd;
    float o7 = fmaxf(a7 * disd + bh.w, 0.0f) * disd;
    uint4 o;
    o.x = rne_bf16(o0) | (rne_bf16(o1) << 16);
    o.y = rne_bf16(o2) | (rne_bf16(o3) << 16);
    o.z = rne_bf16(o4) | (rne_bf16(o5) << 16);
    o.w = rne_bf16(o6) | (rne_bf16(o7) << 16);
    ((uint4*)h1s)[(d << 6) + t] = o;
}

// One block (64 threads) per target: g[t] = dis[d]*(sum_s h1s[s] + h1s[d]), d = reg_id[t].
// Output packed bf16 for the MFMA GEMM. Edge loop unrolled x2.
__global__ void layer2_agg_kernel(const u32* __restrict__ h1s, const int* __restrict__ reg_id,
                                  const int* __restrict__ row_start, const int* __restrict__ sorted_src,
                                  const float* __restrict__ dis, u32* __restrict__ g_bf) {
    int tgt = blockIdx.x;
    int d = reg_id[tgt];
    int t = threadIdx.x;
    float disd = dis[d];
    const uint4* base = (const uint4*)h1s;

    uint4 w = base[(d << 6) + t];
    float a0 = bf_lo(w.x), a1 = bf_hi(w.x), a2 = bf_lo(w.y), a3 = bf_hi(w.y);
    float a4 = bf_lo(w.z), a5 = bf_hi(w.z), a6 = bf_lo(w.w), a7 = bf_hi(w.w);
    float c0 = 0, c1 = 0, c2 = 0, c3 = 0, c4 = 0, c5 = 0, c6 = 0, c7 = 0;

    int beg = row_start[d], end = row_start[d + 1];
    int i = beg;
    if ((end - beg) & 1) {
        int s = sorted_src[i++];
        uint4 ws = base[(s << 6) + t];
        a0 += bf_lo(ws.x); a1 += bf_hi(ws.x);
        a2 += bf_lo(ws.y); a3 += bf_hi(ws.y);
        a4 += bf_lo(ws.z); a5 += bf_hi(ws.z);
        a6 += bf_lo(ws.w); a7 += bf_hi(ws.w);
    }
    for (; i < end; i += 2) {
        int s0 = sorted_src[i];
        int s1 = sorted_src[i + 1];
        uint4 w0 = base[(s0 << 6) + t];
        uint4 w1 = base[(s1 << 6) + t];
        a0 += bf_lo(w0.x); a1 += bf_hi(w0.x);
        a2 += bf_lo(w0.y); a3 += bf_hi(w0.y);
        a4 += bf_lo(w0.z); a5 += bf_hi(w0.z);
        a6 += bf_lo(w0.w); a7 += bf_hi(w0.w);
        c0 += bf_lo(w1.x); c1 += bf_hi(w1.x);
        c2 += bf_lo(w1.y); c3 += bf_hi(w1.y);
        c4 += bf_lo(w1.z); c5 += bf_hi(w1.z);
        c6 += bf_lo(w1.w); c7 += bf_hi(w1.w);
    }
    a0 += c0; a1 += c1; a2 += c2; a3 += c3;
    a4 += c4; a5 += c5; a6 += c6; a7 += c7;

    uint4 o;
    o.x = rne_bf16(a0 * disd) | (rne_bf16(a1 * disd) << 16);
    o.y = rne_bf16(a2 * disd) | (rne_bf16(a3 * disd) << 16);
    o.z = rne_bf16(a4 * disd) | (rne_bf16(a5 * disd) << 16);
    o.w = rne_bf16(a6 * disd) | (rne_bf16(a7 * disd) << 16);
    ((uint4*)g_bf)[(tgt << 6) + t] = o;
}

// out = g @ W2 + b2 via MFMA.  M=2048, K=512, N=128.
// One wave per 16x16 output tile: 1024 waves = 256 blocks x 4 waves.
// D: col = lane&15, row = (lane>>4)*4 + reg  [m89-verified].
__global__ void gemm_out_mfma(const u32* __restrict__ g_bf, const u32* __restrict__ w2t_bf,
                              const float* __restrict__ b2, float* __restrict__ out) {
    int w = blockIdx.x * 4 + (threadIdx.x >> 6);   // 0..1023
    int lane = threadIdx.x & 63;
    int tm = w >> 3;        // 0..127
    int tn = w & 7;         // 0..7
    int r15 = lane & 15;
    int kb4 = (lane >> 4) << 2;   // u32 offset of this lane's k-block

    const uint4* arow = (const uint4*)(g_bf + ((tm * 16 + r15) << 8) + kb4);
    const uint4* brow = (const uint4*)(w2t_bf + ((tn * 16 + r15) << 8) + kb4);
    frag_cd acc = {0.0f, 0.0f, 0.0f, 0.0f};
#pragma unroll
    for (int kk = 0; kk < 16; kk++) {
        uint4 av = arow[kk * 4];   // +16 u32 per K-step of 32
        uint4 bv = brow[kk * 4];
        acc = __builtin_amdgcn_mfma_f32_16x16x32_bf16(*(frag_ab*)&av, *(frag_ab*)&bv, acc, 0, 0, 0);
    }
    int col = tn * 16 + r15;
    int row0 = tm * 16 + ((lane >> 4) << 2);
    float bias = b2[col];
#pragma unroll
    for (int r = 0; r < 4; r++)
        out[(size_t)(row0 + r) * R_EMB + col] = acc[r] + bias;
}

extern "C" void kernel_launch(void* const* d_in, const int* in_sizes, int n_in,
                              void* d_out, int out_size, void* d_ws, size_t ws_size,
                              hipStream_t stream) {
    const int* reg_id = (const int*)d_in[0];
    const int* edge = (const int*)d_in[1];
    const float* W1 = (const float*)d_in[2];
    const float* b1 = (const float*)d_in[3];
    const float* W2 = (const float*)d_in[4];
    const float* b2 = (const float*)d_in[5];
    float* out = (float*)d_out;

    char* ws = (char*)d_ws;
    int* deg = (int*)(ws + OFF_DEG);
    int* row_start = (int*)(ws + OFF_ROWSTART);
    int* cursor = (int*)(ws + OFF_CURSOR);
    float* dis = (float*)(ws + OFF_DIS);
    int* sorted_src = (int*)(ws + OFF_SORTED);
    u32* W1s = (u32*)(ws + OFF_W1S);
    u32* h1s = (u32*)(ws + OFF_H1S);
    u32* w2t = (u32*)(ws + OFF_W2T);
    u32* g_bf = (u32*)(ws + OFF_G);

    hipMemsetAsync(deg, 0, N_NODE * sizeof(int), stream);

    hist_kernel<<<N_EDGE / 256, 256, 0, stream>>>(edge, deg);
    scan_kernel<<<1, 1024, 0, stream>>>(deg, row_start, cursor, dis);
    prep_kernel<<<1024 + 8192 + 128, 256, 0, stream>>>(edge, cursor, sorted_src,
                                                       W1, dis, W1s, W2, w2t);
    layer1_kernel<<<N_NODE, 64, 0, stream>>>(W1s, b1, row_start, sorted_src, dis, h1s);
    layer2_agg_kernel<<<N_REG, 64, 0, stream>>>(h1s, reg_id, row_start, sorted_src, dis, g_bf);
    gemm_out_mfma<<<256, 256, 0, stream>>>(g_bf, w2t, b2, out);
}